// Round 15
// baseline (272.081 us; speedup 1.0000x reference)
//
#include <hip/hip_runtime.h>
#include <hip/hip_bf16.h>
#include <hip/hip_cooperative_groups.h>

namespace cg = cooperative_groups;

// Problem constants (match reference)
#define Bb   32
#define Nn   65536
#define Dd   16
#define Hh   64
#define Mm   32
#define OUTn 3

#define TPB    256
#define NPW    512                  // nodes per wave (16 tiles of 32)
#define SEGN   (NPW * 4)            // 2048 nodes per block (4 waves)
#define NBLK   ((Bb * Nn) / SEGN)   // 1024 blocks (4/CU; ~8KiB LDS -> validator-safe)
#define WPBATCH 128                 // partial rows per batch (32 blocks x 4 waves)
#define NSEG   65                   // 64 knots -> 65 segments

typedef __attribute__((ext_vector_type(8)))  __bf16 bf16x8;
typedef __attribute__((ext_vector_type(4)))  __bf16 bf16x4;
typedef __attribute__((ext_vector_type(16))) float  f32x16;
typedef __attribute__((ext_vector_type(4)))  float  f32x4;

static __device__ inline void split_bf(float w, __bf16& hi, __bf16& lo) {
    hi = (__bf16)w;                 // RNE hardware cvt
    lo = (__bf16)(w - (float)hi);   // residual
}

// ---------------------------------------------------------------------------
// Shared device helpers (used by fused and fallback paths)

// one 32-node MFMA tile: va/vb = 8 feats (k-slice 'half') of node tile*32+l31
#define TILE_BODY(va, vb)                                                       \
    bf16x8 a;                                                                   \
    a[0] = (__bf16)va[0]; a[1] = (__bf16)va[1];                                 \
    a[2] = (__bf16)va[2]; a[3] = (__bf16)va[3];                                 \
    a[4] = (__bf16)vb[0]; a[5] = (__bf16)vb[1];                                 \
    a[6] = (__bf16)vb[2]; a[7] = (__bf16)vb[3];                                 \
    f32x16 z{};                                                                 \
    f32x16 accA = __builtin_amdgcn_mfma_f32_32x32x16_bf16(a, bloA, z, 0, 0, 0); \
    accA        = __builtin_amdgcn_mfma_f32_32x32x16_bf16(a, bhiA, accA, 0, 0, 0);\
    f32x16 accB = __builtin_amdgcn_mfma_f32_32x32x16_bf16(a, bloB, z, 0, 0, 0); \
    accB        = __builtin_amdgcn_mfma_f32_32x32x16_bf16(a, bhiB, accB, 0, 0, 0);\
    _Pragma("unroll")                                                           \
    for (int r = 0; r < 16; ++r) {                                              \
        accA[r] = fmaxf(accA[r] + biasA, 0.f);                                  \
        accB[r] = fmaxf(accB[r] + biasB, 0.f);                                  \
    }                                                                           \
    _Pragma("unroll")                                                           \
    for (int st = 8; st >= 1; st >>= 1)                                         \
        _Pragma("unroll")                                                       \
        for (int r = 0; r < st; ++r) {                                          \
            accA[r] += accA[r + st];                                            \
            accB[r] += accB[r + st];                                            \
        }                                                                       \
    hsumA += accA[0]; hsumB += accB[0];

#define LOAD_BFRAGS()                                                           \
    bf16x8 bhiA, bloA, bhiB, bloB;                                              \
    _Pragma("unroll")                                                           \
    for (int e = 0; e < 8; ++e) {                                               \
        const int k = 8 * half + e;                                             \
        __bf16 h, l;                                                            \
        split_bf(mw1[k * Hh + l31], h, l);        bhiA[e] = h; bloA[e] = l;     \
        split_bf(mw1[k * Hh + 32 + l31], h, l);   bhiB[e] = h; bloB[e] = l;     \
    }                                                                           \
    const float biasA = mb1[l31];                                               \
    const float biasB = mb1[32 + l31];

// PWL table build from sHs (per-batch). Needs scr: 800-float scratch laid out
// below; 256 threads. Writes knotsG/segG for batch b.
#define COMBINE_BODY(scr, b, t)                                                 \
    float* sHs   = (scr);                                                       \
    float* sMs   = (scr) + 64;                                                  \
    float* sBase = (scr) + 96;                                                  \
    float* sW    = (scr) + 160;                                                 \
    float* sKn   = (scr) + 224;                                                 \
    float* sSort = (scr) + 288;                                                 \
    float* sIw2  = (scr) + 352;   /* 192 */                                     \
    if ((t) < Mm) {                                                             \
        float v = (float)Nn * mb2[t];                                           \
        for (int hh = 0; hh < Hh; ++hh) v = fmaf(sHs[hh], mw2[hh * Mm + (t)], v);\
        sMs[t] = v;                                                             \
    }                                                                           \
    __syncthreads();                                                            \
    if ((t) < Hh) {                                                             \
        float bs = ib1[t];                                                      \
        for (int m = 0; m < Mm; ++m) bs = fmaf(sMs[m], iw1[m * Hh + (t)], bs);  \
        float wv = iw1[Mm * Hh + (t)];                                          \
        sBase[t] = bs; sW[t] = wv;                                              \
        float kk = (wv != 0.f) ? (-bs / wv) : 1e15f;                            \
        if (!(fabsf(kk) < 1e15f)) kk = 1e15f;                                   \
        sKn[t] = kk;                                                            \
    }                                                                           \
    __syncthreads();                                                            \
    if ((t) < Hh) {                                                             \
        float kk = sKn[t];                                                      \
        int r = 0;                                                              \
        for (int j = 0; j < Hh; ++j) {                                          \
            float kj = sKn[j];                                                  \
            r += (kj < kk || (kj == kk && j < (t))) ? 1 : 0;                    \
        }                                                                       \
        sSort[r] = kk;                                                          \
    }                                                                           \
    __syncthreads();                                                            \
    if ((t) < Hh) knotsG[(size_t)(b) * Hh + (t)] = sSort[t];                    \
    if ((t) < NSEG) {                                                           \
        float lo = ((t) == 0)  ? sSort[0] - 1.0f      : sSort[(t) - 1];         \
        float hi = ((t) == Hh) ? sSort[Hh - 1] + 1.0f : sSort[t];               \
        float m  = 0.5f * lo + 0.5f * hi;                                       \
        float A0 = ib2[0], A1 = ib2[1], A2 = ib2[2];                            \
        float B0 = 0.f, B1 = 0.f, B2 = 0.f;                                     \
        for (int hh = 0; hh < Hh; ++hh) {                                       \
            float bs = sBase[hh], wv = sW[hh];                                  \
            if (fmaf(wv, m, bs) > 0.f) {                                        \
                A0 = fmaf(bs, sIw2[hh * 3 + 0], A0);                            \
                A1 = fmaf(bs, sIw2[hh * 3 + 1], A1);                            \
                A2 = fmaf(bs, sIw2[hh * 3 + 2], A2);                            \
                B0 = fmaf(wv, sIw2[hh * 3 + 0], B0);                            \
                B1 = fmaf(wv, sIw2[hh * 3 + 1], B1);                            \
                B2 = fmaf(wv, sIw2[hh * 3 + 2], B2);                            \
            }                                                                   \
        }                                                                       \
        float* sg = segG + (size_t)(b) * 6 * NSEG;                              \
        sg[0 * NSEG + (t)] = A0; sg[1 * NSEG + (t)] = A1; sg[2 * NSEG + (t)] = A2;\
        sg[3 * NSEG + (t)] = B0; sg[4 * NSEG + (t)] = B1; sg[5 * NSEG + (t)] = B2;\
    }

// ---------------------------------------------------------------------------
// FUSED cooperative kernel. LDS ~= 4KiB xs + 3.2KiB overlay.
__global__ __launch_bounds__(TPB) void k_fused(
    const float* __restrict__ in,
    const float* __restrict__ mw1, const float* __restrict__ mb1,
    const float* __restrict__ mw2, const float* __restrict__ mb2,
    const float* __restrict__ iw1, const float* __restrict__ ib1,
    const float* __restrict__ iw2, const float* __restrict__ ib2,
    float* __restrict__ out,
    float* __restrict__ partials, float* __restrict__ knotsG,
    float* __restrict__ segG)
{
    cg::grid_group grid = cg::this_grid();

    __shared__ __bf16 xs[SEGN];                     // 4 KiB, lives A->C
    __shared__ float  ov[816];                      // B scratch / C tables

    const int tid  = threadIdx.x;
    const int lane = tid & 63;
    const int w    = tid >> 6;                      // wave (0..3)
    const int l31  = lane & 31;
    const int half = lane >> 5;
    const size_t blk0 = (size_t)blockIdx.x * SEGN;

    // ---------------- Phase A: register-stream MFMA ----------------
    {
        LOAD_BFRAGS();
        float hsumA = 0.f, hsumB = 0.f;
        const float* __restrict__ inw =
            in + (blk0 + (size_t)w * NPW) * Dd + (size_t)l31 * Dd + 8 * half;

#pragma unroll 1
        for (int s = 0; s < NPW / 32; ++s) {        // 16 tiles of 32 nodes
            const float* ap = inw + (size_t)s * 32 * Dd;
            f32x4 v0 = *(const f32x4*)ap;
            f32x4 v1 = *(const f32x4*)(ap + 4);
            TILE_BODY(v0, v1);
            float x15 = __shfl_xor(v1[3], 32, 64);  // feat 15 of node s*32+l31
            if (lane < 32) xs[w * NPW + s * 32 + lane] = (__bf16)x15;
        }

        hsumA += __shfl_xor(hsumA, 32, 64);
        hsumB += __shfl_xor(hsumB, 32, 64);
        const int wid = blockIdx.x * 4 + w;
        partials[(size_t)wid * Hh + lane] = (lane < 32) ? hsumA : hsumB;
    }

    grid.sync();

    // ---------------- Phase B: blocks 0..31 build PWL tables ----------------
    if (blockIdx.x < Bb) {
        const int b = blockIdx.x;
        const int t = tid;
        const int h = t & 63, slice = t >> 6;       // 4 slices x 32 rows
        float (*red)[Hh] = (float (*)[Hh])(ov + 560);  // 4 x 64

        float s = 0.f;
        const float* p = partials + ((size_t)b * WPBATCH + slice * 32) * Hh + h;
#pragma unroll 8
        for (int ww = 0; ww < 32; ++ww) s += p[(size_t)ww * Hh];
        red[slice][h] = s;
        for (int i = t; i < Hh * OUTn; i += TPB) ov[352 + i] = iw2[i];
        __syncthreads();
        if (t < Hh) ov[t] = red[0][t] + red[1][t] + red[2][t] + red[3][t]; // sHs
        __syncthreads();
        COMBINE_BODY(ov, b, t);
    }

    grid.sync();

    // ---------------- Phase C: PWL eval from LDS xs ----------------
    {
        const int bt = blockIdx.x >> 5;             // 32 blocks per batch
        float* sK = ov;                             // 64 knots
        float* sT = ov + Hh;                        // 390 floats

        if (tid < Hh) sK[tid] = knotsG[(size_t)bt * Hh + tid];
        for (int i = tid; i < 6 * NSEG; i += TPB)
            sT[i] = segG[(size_t)bt * 6 * NSEG + i];
        __syncthreads();

#pragma unroll
        for (int k = 0; k < SEGN / (TPB * 4); ++k) {    // 2 iters, 4 nodes/thr
            const int ln4 = (k * TPB + tid) * 4;
            bf16x4 xv = *(const bf16x4*)(xs + ln4);
            float o[12];
#pragma unroll
            for (int i = 0; i < 4; ++i) {
                const float x = (float)xv[i];
                int pos = 0;
#pragma unroll
                for (int st = 32; st >= 1; st >>= 1)
                    pos += (sK[pos + st - 1] < x) ? st : 0;
                pos += (sK[pos] < x) ? 1 : 0;
                o[3 * i + 0] = fmaf(sT[3 * NSEG + pos], x, sT[0 * NSEG + pos]);
                o[3 * i + 1] = fmaf(sT[4 * NSEG + pos], x, sT[1 * NSEG + pos]);
                o[3 * i + 2] = fmaf(sT[5 * NSEG + pos], x, sT[2 * NSEG + pos]);
            }
            f32x4* po = (f32x4*)(out + (blk0 + (size_t)ln4) * 3);
            po[0] = f32x4{o[0], o[1], o[2],  o[3]};
            po[1] = f32x4{o[4], o[5], o[6],  o[7]};
            po[2] = f32x4{o[8], o[9], o[10], o[11]};
        }
    }
}

// ---------------------------------------------------------------------------
// FALLBACK path (3 kernels) -- used only if cooperative launch is rejected.
__global__ __launch_bounds__(TPB) void k_mphase(
    const float* __restrict__ in, const float* __restrict__ mw1,
    const float* __restrict__ mb1, float* __restrict__ partials,
    __bf16* __restrict__ xlast)
{
    const int lane = threadIdx.x & 63;
    const int l31  = lane & 31;
    const int half = lane >> 5;
    const int wid  = blockIdx.x * (TPB / 64) + (threadIdx.x >> 6);
    const size_t node0 = (size_t)wid * NPW;

    LOAD_BFRAGS();
    float hsumA = 0.f, hsumB = 0.f;
    const float* __restrict__ inw = in + node0 * Dd + (size_t)l31 * Dd + 8 * half;

#pragma unroll 1
    for (int s = 0; s < NPW / 32; ++s) {
        const float* ap = inw + (size_t)s * 32 * Dd;
        f32x4 v0 = *(const f32x4*)ap;
        f32x4 v1 = *(const f32x4*)(ap + 4);
        TILE_BODY(v0, v1);
        float x15 = __shfl_xor(v1[3], 32, 64);
        if (lane < 32) xlast[node0 + (size_t)s * 32 + lane] = (__bf16)x15;
    }

    hsumA += __shfl_xor(hsumA, 32, 64);
    hsumB += __shfl_xor(hsumB, 32, 64);
    partials[(size_t)wid * Hh + lane] = (lane < 32) ? hsumA : hsumB;
}

__global__ __launch_bounds__(256) void k_combine(
    const float* __restrict__ partials,
    const float* __restrict__ mw2, const float* __restrict__ mb2,
    const float* __restrict__ iw1, const float* __restrict__ ib1,
    const float* __restrict__ iw2, const float* __restrict__ ib2,
    float* __restrict__ knotsG, float* __restrict__ segG)
{
    __shared__ float ov[816];
    const int b = blockIdx.x;
    const int t = threadIdx.x;
    const int h = t & 63, slice = t >> 6;
    float (*red)[Hh] = (float (*)[Hh])(ov + 560);

    float s = 0.f;
    const float* p = partials + ((size_t)b * WPBATCH + slice * 32) * Hh + h;
#pragma unroll 8
    for (int ww = 0; ww < 32; ++ww) s += p[(size_t)ww * Hh];
    red[slice][h] = s;
    for (int i = t; i < Hh * OUTn; i += 256) ov[352 + i] = iw2[i];
    __syncthreads();
    if (t < Hh) ov[t] = red[0][t] + red[1][t] + red[2][t] + red[3][t];
    __syncthreads();
    COMBINE_BODY(ov, b, t);
}

__global__ __launch_bounds__(TPB) void k_iphase(
    const __bf16* __restrict__ xl, const float* __restrict__ knotsG,
    const float* __restrict__ segG, float* __restrict__ out)
{
    __shared__ __align__(16) float sK[Hh];
    __shared__ float sT[6 * NSEG];
    const int t = threadIdx.x;
    const int b = blockIdx.x >> 6;

    if (t < Hh) sK[t] = knotsG[(size_t)b * Hh + t];
    for (int i = t; i < 6 * NSEG; i += TPB) sT[i] = segG[(size_t)b * 6 * NSEG + i];
    __syncthreads();

    const size_t n0 = ((size_t)blockIdx.x * TPB + t) * 4;
    bf16x4 xv = *(const bf16x4*)(xl + n0);
    float o[12];
#pragma unroll
    for (int i = 0; i < 4; ++i) {
        const float x = (float)xv[i];
        int pos = 0;
#pragma unroll
        for (int st = 32; st >= 1; st >>= 1)
            pos += (sK[pos + st - 1] < x) ? st : 0;
        pos += (sK[pos] < x) ? 1 : 0;
        o[3 * i + 0] = fmaf(sT[3 * NSEG + pos], x, sT[0 * NSEG + pos]);
        o[3 * i + 1] = fmaf(sT[4 * NSEG + pos], x, sT[1 * NSEG + pos]);
        o[3 * i + 2] = fmaf(sT[5 * NSEG + pos], x, sT[2 * NSEG + pos]);
    }
    f32x4* po = (f32x4*)(out + n0 * 3);
    po[0] = f32x4{o[0], o[1], o[2],  o[3]};
    po[1] = f32x4{o[4], o[5], o[6],  o[7]};
    po[2] = f32x4{o[8], o[9], o[10], o[11]};
}

// ---------------------------------------------------------------------------
extern "C" void kernel_launch(void* const* d_in, const int* in_sizes, int n_in,
                              void* d_out, int out_size, void* d_ws, size_t ws_size,
                              hipStream_t stream) {
    const float* in  = (const float*)d_in[0];
    const float* mw1 = (const float*)d_in[1];
    const float* mb1 = (const float*)d_in[2];
    const float* mw2 = (const float*)d_in[3];
    const float* mb2 = (const float*)d_in[4];
    const float* iw1 = (const float*)d_in[5];
    const float* ib1 = (const float*)d_in[6];
    const float* iw2 = (const float*)d_in[7];
    const float* ib2 = (const float*)d_in[8];
    float* out = (float*)d_out;

    char* ws = (char*)d_ws;
    const size_t PART_SZ = (size_t)NBLK * 4 * Hh * sizeof(float);  // 1 MiB
    float*  partials = (float*)(ws);
    float*  knotsG   = (float*)(ws + PART_SZ);             // 8 KiB
    float*  segG     = (float*)(ws + PART_SZ + 8192);      // ~49 KiB
    __bf16* xl       = (__bf16*)(ws + PART_SZ + 131072);   // 4 MiB (fallback only)

    void* args[] = {
        (void*)&in, (void*)&mw1, (void*)&mb1, (void*)&mw2, (void*)&mb2,
        (void*)&iw1, (void*)&ib1, (void*)&iw2, (void*)&ib2, (void*)&out,
        (void*)&partials, (void*)&knotsG, (void*)&segG
    };
    hipError_t err = hipLaunchCooperativeKernel((const void*)k_fused,
                                                dim3(NBLK), dim3(TPB),
                                                args, 0, stream);
    if (err != hipSuccess) {
        // fallback: 3-kernel pipeline (known-good 52us path)
        const int nwaves  = (Bb * Nn) / NPW;          // 4096
        const int nblocks = nwaves / (TPB / 64);      // 1024
        hipLaunchKernelGGL(k_mphase, dim3(nblocks), dim3(TPB), 0, stream,
                           in, mw1, mb1, partials, xl);
        hipLaunchKernelGGL(k_combine, dim3(Bb), dim3(256), 0, stream,
                           partials, mw2, mb2, iw1, ib1, iw2, ib2, knotsG, segG);
        hipLaunchKernelGGL(k_iphase, dim3((Bb * Nn) / (TPB * 4)), dim3(TPB), 0, stream,
                           xl, knotsG, segG, out);
    }
}

// Round 16
// 50.859 us; speedup vs baseline: 5.3497x; 5.3497x over previous
//
#include <hip/hip_runtime.h>
#include <hip/hip_bf16.h>

// Problem constants (match reference)
#define Bb   32
#define Nn   65536
#define Dd   16
#define Hh   64
#define Mm   32
#define OUTn 3

#define TPB    256
#define CHUNK  256                  // nodes per LDS chunk (16 KiB fp32)
#define NCH    8                    // chunks per mphase block
#define SEGN   (CHUNK * NCH)        // 2048 nodes per mphase block
#define NWAVES ((Bb * Nn) / 512)    // 4096 waves (each wave: 512 nodes)
#define WPB    (NWAVES / Bb)        // 128 partial rows per batch
#define NSEG   65                   // 64 knots -> 65 segments

// iphase2 geometry
#define IBLK   512                  // iphase blocks
#define INODES ((Bb * Nn) / IBLK)   // 4096 nodes per iphase block
#define IBPB   (IBLK / Bb)          // 16 blocks per batch

typedef __attribute__((ext_vector_type(8)))  __bf16 bf16x8;
typedef __attribute__((ext_vector_type(4)))  __bf16 bf16x4;
typedef __attribute__((ext_vector_type(16))) float  f32x16;
typedef __attribute__((ext_vector_type(4)))  float  f32x4;

static __device__ inline void split_bf(float w, __bf16& hi, __bf16& lo) {
    hi = (__bf16)w;                 // RNE hardware cvt
    lo = (__bf16)(w - (float)hi);   // residual
}

// async 16B global->LDS (dest = wave-uniform base + lane*16)
typedef const __attribute__((address_space(1))) unsigned int gu32;
typedef __attribute__((address_space(3))) unsigned int lu32;
static __device__ __forceinline__ void gld16(const float* g, float* l) {
    __builtin_amdgcn_global_load_lds((gu32*)g, (lu32*)l, 16, 0, 0);
}

// ---------------------------------------------------------------------------
// Phase 1 via MFMA, LDS double-buffered streaming (R14 structure, REP removed;
// measured 20.3 us warm marginal = HBM/L3 roofline for the 134MB stream).
__global__ __launch_bounds__(TPB) void k_mphase(
    const float* __restrict__ in, const float* __restrict__ mw1,
    const float* __restrict__ mb1, float* __restrict__ partials,
    __bf16* __restrict__ xlast)
{
    __shared__ float lds[2][CHUNK * Dd];            // 2 x 16 KiB

    const int tid  = threadIdx.x;
    const int lane = tid & 63;
    const int w    = tid >> 6;                      // wave in block (0..3)
    const int l31  = lane & 31;
    const int half = lane >> 5;
    const size_t blk0 = (size_t)blockIdx.x * SEGN;  // first node of this block

    // B fragments: B[k][col], k = 8*half + e. hi/lo split kills weight bias.
    bf16x8 bhiA, bloA, bhiB, bloB;
#pragma unroll
    for (int e = 0; e < 8; ++e) {
        const int k = 8 * half + e;
        __bf16 h, l;
        split_bf(mw1[k * Hh + l31], h, l);        bhiA[e] = h; bloA[e] = l;
        split_bf(mw1[k * Hh + 32 + l31], h, l);   bhiB[e] = h; bloB[e] = l;
    }
    const float biasA = mb1[l31];
    const float biasB = mb1[32 + l31];

    // stage chunk c into buffer bf: node = tid, quarter q -> granule q*CHUNK+tid
    auto stage = [&](int bf, int c) {
        const float* src = in + (blk0 + (size_t)c * CHUNK + tid) * Dd;
#pragma unroll
        for (int q = 0; q < 4; ++q)
            gld16(src + q * 4, &lds[bf][(size_t)(q * CHUNK) * 4 + (size_t)w * 256]);
    };

    float hsumA = 0.f, hsumB = 0.f;
    int cur = 0;
    stage(0, 0);
    __syncthreads();                                // chunk 0 ready

#pragma unroll 1
    for (int c = 0; c < NCH; ++c) {
        if (c + 1 < NCH) stage(cur ^ 1, c + 1);     // prefetch next chunk

#pragma unroll
        for (int T = 0; T < 2; ++T) {               // 2 tiles of 32 nodes per wave
            const int nb = w * 64 + T * 32 + l31;
            const int q0 = half * 2;
            f32x4 v0 = *(const f32x4*)&lds[cur][(size_t)(q0 * CHUNK + nb) * 4];
            f32x4 v1 = *(const f32x4*)&lds[cur][(size_t)((q0 + 1) * CHUNK + nb) * 4];

            bf16x8 a;
            a[0] = (__bf16)v0[0]; a[1] = (__bf16)v0[1];
            a[2] = (__bf16)v0[2]; a[3] = (__bf16)v0[3];
            a[4] = (__bf16)v1[0]; a[5] = (__bf16)v1[1];
            a[6] = (__bf16)v1[2]; a[7] = (__bf16)v1[3];

            f32x16 z{};
            f32x16 accA = __builtin_amdgcn_mfma_f32_32x32x16_bf16(a, bloA, z, 0, 0, 0);
            accA        = __builtin_amdgcn_mfma_f32_32x32x16_bf16(a, bhiA, accA, 0, 0, 0);
            f32x16 accB = __builtin_amdgcn_mfma_f32_32x32x16_bf16(a, bloB, z, 0, 0, 0);
            accB        = __builtin_amdgcn_mfma_f32_32x32x16_bf16(a, bhiB, accB, 0, 0, 0);

#pragma unroll
            for (int r = 0; r < 16; ++r) {
                accA[r] = fmaxf(accA[r] + biasA, 0.f);
                accB[r] = fmaxf(accB[r] + biasB, 0.f);
            }
#pragma unroll
            for (int st = 8; st >= 1; st >>= 1)
#pragma unroll
                for (int r = 0; r < st; ++r) {
                    accA[r] += accA[r + st];
                    accB[r] += accB[r + st];
                }
            hsumA += accA[0]; hsumB += accB[0];

            // x_last: half=1 lanes hold feat 15 of node nb in v1[3]
            float x15 = __shfl_xor(v1[3], 32, 64);
            if (lane < 32)
                xlast[blk0 + (size_t)c * CHUNK + w * 64 + T * 32 + lane] = (__bf16)x15;
        }

        __syncthreads();       // drains staged loads; releases cur
        cur ^= 1;
    }

    hsumA += __shfl_xor(hsumA, 32, 64);
    hsumB += __shfl_xor(hsumB, 32, 64);
    const int wid = blockIdx.x * 4 + w;
    partials[(size_t)wid * Hh + lane] = (lane < 32) ? hsumA : hsumB;
}

// ---------------------------------------------------------------------------
// Phase 2 (fused): each block REDUNDANTLY builds its batch's PWL tables in LDS
// (reduce partials -> msg_sum -> base/w -> sorted knots -> 65 segments), then
// evaluates its 4096 nodes. No global table round-trip, one fewer graph node.
__global__ __launch_bounds__(TPB) void k_iphase2(
    const __bf16* __restrict__ xl, const float* __restrict__ partials,
    const float* __restrict__ mw2, const float* __restrict__ mb2,
    const float* __restrict__ iw1, const float* __restrict__ ib1,
    const float* __restrict__ iw2, const float* __restrict__ ib2,
    float* __restrict__ out)
{
    __shared__ __align__(16) float sK[Hh];          // sorted knots
    __shared__ float sT[6 * NSEG];                  // segment tables (SoA)
    __shared__ float scr[544];                      // sHs,sMs,sBase,sW,sKn,sIw2
    __shared__ float red[4][Hh];

    const int t = threadIdx.x;
    const int b = blockIdx.x / IBPB;                // batch

    // ---- combine (redundant per block; identical values everywhere) ----
    {
        const int h = t & 63, slice = t >> 6;       // 4 slices x 32 rows
        float s = 0.f;
        const float* p = partials + ((size_t)b * WPB + slice * 32) * Hh + h;
#pragma unroll 8
        for (int ww = 0; ww < 32; ++ww) s += p[(size_t)ww * Hh];
        red[slice][h] = s;
        for (int i = t; i < Hh * OUTn; i += TPB) scr[352 + i] = iw2[i];
        __syncthreads();

        float* sHs  = scr;          // 64
        float* sMs  = scr + 64;     // 32
        float* sBase= scr + 96;     // 64
        float* sW   = scr + 160;    // 64
        float* sKn  = scr + 224;    // 64
        float* sIw2 = scr + 352;    // 192

        if (t < Hh) sHs[t] = red[0][t] + red[1][t] + red[2][t] + red[3][t];
        __syncthreads();

        if (t < Mm) {
            float v = (float)Nn * mb2[t];
            for (int hh = 0; hh < Hh; ++hh) v = fmaf(sHs[hh], mw2[hh * Mm + t], v);
            sMs[t] = v;
        }
        __syncthreads();

        if (t < Hh) {
            float bs = ib1[t];
            for (int m = 0; m < Mm; ++m) bs = fmaf(sMs[m], iw1[m * Hh + t], bs);
            float wv = iw1[Mm * Hh + t];
            sBase[t] = bs; sW[t] = wv;
            float kk = (wv != 0.f) ? (-bs / wv) : 1e15f;
            if (!(fabsf(kk) < 1e15f)) kk = 1e15f;   // NaN/inf guard
            sKn[t] = kk;
        }
        __syncthreads();

        if (t < Hh) {                               // rank sort -> sK
            float kk = sKn[t];
            int r = 0;
            for (int j = 0; j < Hh; ++j) {
                float kj = sKn[j];
                r += (kj < kk || (kj == kk && j < t)) ? 1 : 0;
            }
            sK[r] = kk;
        }
        __syncthreads();

        if (t < NSEG) {                             // 65 PWL segments
            float lo = (t == 0)  ? sK[0] - 1.0f      : sK[t - 1];
            float hi = (t == Hh) ? sK[Hh - 1] + 1.0f : sK[t];
            float m  = 0.5f * lo + 0.5f * hi;
            float A0 = ib2[0], A1 = ib2[1], A2 = ib2[2];
            float B0 = 0.f, B1 = 0.f, B2 = 0.f;
            for (int hh = 0; hh < Hh; ++hh) {
                float bs = sBase[hh], wv = sW[hh];
                if (fmaf(wv, m, bs) > 0.f) {
                    A0 = fmaf(bs, sIw2[hh * 3 + 0], A0);
                    A1 = fmaf(bs, sIw2[hh * 3 + 1], A1);
                    A2 = fmaf(bs, sIw2[hh * 3 + 2], A2);
                    B0 = fmaf(wv, sIw2[hh * 3 + 0], B0);
                    B1 = fmaf(wv, sIw2[hh * 3 + 1], B1);
                    B2 = fmaf(wv, sIw2[hh * 3 + 2], B2);
                }
            }
            sT[0 * NSEG + t] = A0; sT[1 * NSEG + t] = A1; sT[2 * NSEG + t] = A2;
            sT[3 * NSEG + t] = B0; sT[4 * NSEG + t] = B1; sT[5 * NSEG + t] = B2;
        }
        __syncthreads();
    }

    // ---- PWL eval: 4096 nodes, 16 per thread ----
    const size_t base = (size_t)blockIdx.x * INODES;
#pragma unroll
    for (int k = 0; k < INODES / (TPB * 4); ++k) {  // 4 iters, 4 nodes/thread
        const size_t n0 = base + (size_t)(k * TPB + t) * 4;
        bf16x4 xv = *(const bf16x4*)(xl + n0);
        float o[12];
#pragma unroll
        for (int i = 0; i < 4; ++i) {
            const float x = (float)xv[i];
            int pos = 0;
#pragma unroll
            for (int st = 32; st >= 1; st >>= 1)
                pos += (sK[pos + st - 1] < x) ? st : 0;
            pos += (sK[pos] < x) ? 1 : 0;           // pos = #knots < x, in [0,64]
            o[3 * i + 0] = fmaf(sT[3 * NSEG + pos], x, sT[0 * NSEG + pos]);
            o[3 * i + 1] = fmaf(sT[4 * NSEG + pos], x, sT[1 * NSEG + pos]);
            o[3 * i + 2] = fmaf(sT[5 * NSEG + pos], x, sT[2 * NSEG + pos]);
        }
        f32x4* po = (f32x4*)(out + n0 * 3);
        po[0] = f32x4{o[0], o[1], o[2],  o[3]};
        po[1] = f32x4{o[4], o[5], o[6],  o[7]};
        po[2] = f32x4{o[8], o[9], o[10], o[11]};
    }
}

// ---------------------------------------------------------------------------
extern "C" void kernel_launch(void* const* d_in, const int* in_sizes, int n_in,
                              void* d_out, int out_size, void* d_ws, size_t ws_size,
                              hipStream_t stream) {
    const float* in  = (const float*)d_in[0];
    const float* mw1 = (const float*)d_in[1];
    const float* mb1 = (const float*)d_in[2];
    const float* mw2 = (const float*)d_in[3];
    const float* mb2 = (const float*)d_in[4];
    const float* iw1 = (const float*)d_in[5];
    const float* ib1 = (const float*)d_in[6];
    const float* iw2 = (const float*)d_in[7];
    const float* ib2 = (const float*)d_in[8];
    float* out = (float*)d_out;

    char* ws = (char*)d_ws;
    const size_t PART_SZ = (size_t)NWAVES * Hh * sizeof(float);  // 1 MiB
    float*  partials = (float*)(ws);
    __bf16* xl       = (__bf16*)(ws + PART_SZ + 131072);         // 4 MiB

    const int nblocks = (Bb * Nn) / SEGN;                        // 1024
    hipLaunchKernelGGL(k_mphase, dim3(nblocks), dim3(TPB), 0, stream,
                       in, mw1, mb1, partials, xl);
    hipLaunchKernelGGL(k_iphase2, dim3(IBLK), dim3(TPB), 0, stream,
                       xl, partials, mw2, mb2, iw1, ib1, iw2, ib2, out);
}